// Round 1
// baseline (562.078 us; speedup 1.0000x reference)
//
#include <hip/hip_runtime.h>

typedef unsigned short ushort_t;
typedef short bf16x8 __attribute__((ext_vector_type(8)));
typedef float floatx4 __attribute__((ext_vector_type(4)));

// ---------- bf16 helpers (bit-level, RNE) ----------
__device__ __forceinline__ float bf2f(ushort_t u) {
    return __uint_as_float(((unsigned)u) << 16);
}
__device__ __forceinline__ ushort_t f2bf(float f) {
    unsigned u = __float_as_uint(f);
    unsigned rnd = 0x7fffu + ((u >> 16) & 1u);
    return (ushort_t)((u + rnd) >> 16);
}

// async global->LDS, 16B per lane. LDS dest must be wave-uniform base +
// lane*16 (it is: chunk layout is (c*256+tid)*16 bytes, lane-linear).
__device__ __forceinline__ void gload_lds16(const void* g, void* l) {
    __builtin_amdgcn_global_load_lds(
        (const __attribute__((address_space(1))) unsigned int*)g,
        (__attribute__((address_space(3))) unsigned int*)l,
        16, 0, 0);
}

// ---------- fp32 -> bf16 batch convert ----------
struct CvtArgs {
    const float* src[12];
    ushort_t* dst[12];
    int n4[12];
};

__global__ __launch_bounds__(256) void cvt_kernel(CvtArgs a) {
    int t = blockIdx.y;
    int n4 = a.n4[t];
    const float4* s = (const float4*)a.src[t];
    ushort_t* d = a.dst[t];
    int stride = gridDim.x * blockDim.x;
    for (int i = blockIdx.x * blockDim.x + threadIdx.x; i < n4; i += stride) {
        float4 v = s[i];
        ushort4 o;
        o.x = f2bf(v.x); o.y = f2bf(v.y); o.z = f2bf(v.z); o.w = f2bf(v.w);
        ((ushort4*)d)[i] = o;
    }
}

// ---------- batched bf16 GEMM: C[M,N] = A[M,K] @ B[N,K]^T * scale (+bias) ---
// m97 structure (learn_hip, 874-912 TF @128^2 on this chip):
//   BK=32, 32 KB double-buffered LDS, global_load_lds width=16 staging
//   (no VGPR round-trip), depth-1 prefetch, barrier drain per K-step.
// Per K-step per wave: 16 MFMA 16x16x32 + 8 ds_read_b128 + 4 global_load_lds.
// XCD swizzle: grid (M/BM, N/BN, NB), x (M) fast; blocks sharing A-rows have
// linear-index stride gridDim.x (multiple of 8) -> same XCD under round-robin
// dispatch -> A rows fetched once per XCD L2.
// LDS fragment order: chunk p = (i*KQ+q)*16+r holds X[i*16+r][q*8..q*8+7];
// global_load_lds dest (c*256+tid)*16 B and ds_read_b128 fragment reads are
// both lane-linear, so staging needs no swizzle.
template<int NB> struct GemmArgs {
    const ushort_t* A[NB];
    const ushort_t* B[NB];
    const float* bias[NB];
    void* C[NB];
    int trans[NB];
};

template<int BM, int BN, int BK, int NB, bool BF16_OUT,
         bool HAS_BIAS, bool ALLOW_TRANS, int MINW>
__global__ __launch_bounds__(256, MINW) void gemm_bf16(
    GemmArgs<NB> args, int M, int N, int K, float scale)
{
    constexpr int KQ = BK / 8;            // 8-elem k-chunks per row
    constexpr int NS = BK / 32;           // MFMA k-substeps per staged tile
    constexpr int MI = BM / 32;           // MFMA row tiles per wave (2x2 waves)
    constexpr int MJ = BN / 32;
    constexpr int CA = BM * BK / (8 * 256);   // staging chunks per thread
    constexpr int CB = BN * BK / (8 * 256);

    __shared__ __align__(16) ushort_t lA[2][BM * BK];
    __shared__ __align__(16) ushort_t lB[2][BN * BK];

    const int z = blockIdx.z;
    const ushort_t* __restrict__ A = args.A[z];
    const ushort_t* __restrict__ B = args.B[z];

    const int tid  = threadIdx.x;
    const int lane = tid & 63;
    const int wave = tid >> 6;
    const int wm   = wave >> 1;
    const int wn   = wave & 1;
    const int quad = lane >> 4;
    const int r16  = lane & 15;

    const int row0 = blockIdx.x * BM;     // x = M dim (fast) -> XCD swizzle
    const int col0 = blockIdx.y * BN;

    floatx4 acc[MI][MJ] = {};

    const ushort_t* gA[CA];
    const ushort_t* gB[CB];
    #pragma unroll
    for (int c = 0; c < CA; c++) {
        int p = c * 256 + tid;
        int i = p / (16 * KQ), q = (p >> 4) % KQ, r = p & 15;
        gA[c] = A + (size_t)(row0 + i * 16 + r) * K + q * 8;
    }
    #pragma unroll
    for (int c = 0; c < CB; c++) {
        int p = c * 256 + tid;
        int i = p / (16 * KQ), q = (p >> 4) % KQ, r = p & 15;
        gB[c] = B + (size_t)(col0 + i * 16 + r) * K + q * 8;
    }

    // issue async loads for one K-tile into LDS set d; advance pointers
    auto stage = [&](int d) {
        #pragma unroll
        for (int c = 0; c < CA; c++) {
            gload_lds16(gA[c], &lA[d][(c * 256 + tid) * 8]);
            gA[c] += BK;
        }
        #pragma unroll
        for (int c = 0; c < CB; c++) {
            gload_lds16(gB[c], &lB[d][(c * 256 + tid) * 8]);
            gB[c] += BK;
        }
    };

    const int T = K / BK;

    stage(0);
    __syncthreads();          // compiler emits vmcnt(0) drain before barrier
    int cur = 0;

    for (int t = 0; t < T; t++) {
        if (t + 1 < T) stage(cur ^ 1);   // prefetch next tile (other buffer)

        #pragma unroll
        for (int ss = 0; ss < NS; ss++) {
            bf16x8 af[MI], bfr[MJ];
            #pragma unroll
            for (int i = 0; i < MI; i++)
                af[i] = *(const bf16x8*)(&lA[cur][
                    (((wm * MI + i) * KQ + ss * 4 + quad) * 16 + r16) * 8]);
            #pragma unroll
            for (int j = 0; j < MJ; j++)
                bfr[j] = *(const bf16x8*)(&lB[cur][
                    (((wn * MJ + j) * KQ + ss * 4 + quad) * 16 + r16) * 8]);

            #pragma unroll
            for (int i = 0; i < MI; i++)
                #pragma unroll
                for (int j = 0; j < MJ; j++)
                    acc[i][j] = __builtin_amdgcn_mfma_f32_16x16x32_bf16(
                        af[i], bfr[j], acc[i][j], 0, 0, 0);
        }

        __syncthreads();      // drains prefetch vmcnt -> next tile ready
        cur ^= 1;
    }

    float bv[MJ];
    if (HAS_BIAS) {
        #pragma unroll
        for (int j = 0; j < MJ; j++)
            bv[j] = args.bias[z][col0 + (wn * MJ + j) * 16 + r16];
    }

    void* C = args.C[z];
    const bool do_trans = ALLOW_TRANS && args.trans[z];

    #pragma unroll
    for (int i = 0; i < MI; i++) {
        const int m_base = row0 + (wm * MI + i) * 16 + quad * 4;
        #pragma unroll
        for (int j = 0; j < MJ; j++) {
            const int n = col0 + (wn * MJ + j) * 16 + r16;
            if (ALLOW_TRANS && do_trans) {
                // C^T layout [N][M], bf16; 4 consecutive m -> one 8B store
                ushort4 o;
                float v0 = acc[i][j][0] * scale; if (HAS_BIAS) v0 += bv[j];
                float v1 = acc[i][j][1] * scale; if (HAS_BIAS) v1 += bv[j];
                float v2 = acc[i][j][2] * scale; if (HAS_BIAS) v2 += bv[j];
                float v3 = acc[i][j][3] * scale; if (HAS_BIAS) v3 += bv[j];
                o.x = f2bf(v0); o.y = f2bf(v1); o.z = f2bf(v2); o.w = f2bf(v3);
                *(ushort4*)((ushort_t*)C + (size_t)n * M + m_base) = o;
            } else {
                #pragma unroll
                for (int r = 0; r < 4; r++) {
                    float v = acc[i][j][r] * scale;
                    if (HAS_BIAS) v += bv[j];
                    size_t off = (size_t)(m_base + r) * N + n;
                    if (BF16_OUT) ((ushort_t*)C)[off] = f2bf(v);
                    else          ((float*)C)[off] = v;
                }
            }
        }
    }
}

// ---------- row softmax, in-place: S[row,0..4095] bf16, fp32 math ----------
struct SmArgs { ushort_t* S[2]; };

__global__ __launch_bounds__(256) void softmax_kernel(SmArgs a) {
    const int N = 4096;
    ushort_t* S = a.S[blockIdx.y];
    const int row = blockIdx.x;
    const int tid = threadIdx.x;
    const int lane = tid & 63;
    const int wave = tid >> 6;

    bf16x8* ptr = (bf16x8*)(S + (size_t)row * N);
    bf16x8 c0 = ptr[2 * tid];
    bf16x8 c1 = ptr[2 * tid + 1];

    float x[16];
    #pragma unroll
    for (int k = 0; k < 8; k++) {
        x[k]     = bf2f((ushort_t)c0[k]);
        x[8 + k] = bf2f((ushort_t)c1[k]);
    }

    float m = -3.4e38f;
    #pragma unroll
    for (int k = 0; k < 16; k++) m = fmaxf(m, x[k]);
    #pragma unroll
    for (int off = 32; off > 0; off >>= 1) m = fmaxf(m, __shfl_xor(m, off));

    __shared__ float redmax[4], redsum[4];
    if (lane == 0) redmax[wave] = m;
    __syncthreads();
    m = fmaxf(fmaxf(redmax[0], redmax[1]), fmaxf(redmax[2], redmax[3]));

    float s = 0.f;
    #pragma unroll
    for (int k = 0; k < 16; k++) { x[k] = __expf(x[k] - m); s += x[k]; }
    #pragma unroll
    for (int off = 32; off > 0; off >>= 1) s += __shfl_xor(s, off);
    if (lane == 0) redsum[wave] = s;
    __syncthreads();
    s = redsum[0] + redsum[1] + redsum[2] + redsum[3];
    const float inv = 1.0f / s;

    bf16x8 o0, o1;
    #pragma unroll
    for (int k = 0; k < 8; k++) {
        o0[k] = (short)f2bf(x[k] * inv);
        o1[k] = (short)f2bf(x[8 + k] * inv);
    }
    ptr[2 * tid]     = o0;
    ptr[2 * tid + 1] = o1;
}

// ---------- launch ----------
extern "C" void kernel_launch(void* const* d_in, const int* in_sizes, int n_in,
                              void* d_out, int out_size, void* d_ws, size_t ws_size,
                              hipStream_t stream) {
    (void)in_sizes; (void)n_in; (void)out_size;
    const int NC = 4096, NP = 4096, D = 1024;

    char* ws = (char*)d_ws;
    size_t off = 0;
    auto alloc = [&](size_t b) { size_t o = off; off += (b + 255) & ~(size_t)255; return o; };

    ushort_t* xb[6];
    for (int i = 0; i < 6; i++) xb[i] = (ushort_t*)(ws + alloc((size_t)NC * D * 2));
    ushort_t* wb[6];
    for (int i = 0; i < 6; i++) wb[i] = (ushort_t*)(ws + alloc((size_t)D * D * 2));
    ushort_t* qc  = (ushort_t*)(ws + alloc((size_t)NC * D * 2));
    ushort_t* kc  = (ushort_t*)(ws + alloc((size_t)NC * D * 2));
    ushort_t* qp  = (ushort_t*)(ws + alloc((size_t)NP * D * 2));
    ushort_t* kp  = (ushort_t*)(ws + alloc((size_t)NP * D * 2));
    ushort_t* vcT = (ushort_t*)(ws + alloc((size_t)NC * D * 2)); // [D][NC]
    ushort_t* vpT = (ushort_t*)(ws + alloc((size_t)NP * D * 2)); // [D][NP]
    ushort_t* Sb1 = (ushort_t*)(ws + alloc((size_t)4096 * 4096 * 2));
    ushort_t* Sb2 = (ushort_t*)(ws + alloc((size_t)4096 * 4096 * 2));

    if (ws_size < off) return;

    // convert inputs + weights to bf16 (one dispatch)
    CvtArgs ca;
    for (int i = 0; i < 6; i++) {
        ca.src[i] = (const float*)d_in[i];
        ca.dst[i] = xb[i];
        ca.n4[i] = NC * D / 4;
    }
    const int widx[6] = {6, 8, 10, 12, 14, 16};
    for (int i = 0; i < 6; i++) {
        ca.src[6 + i] = (const float*)d_in[widx[i]];
        ca.dst[6 + i] = wb[i];
        ca.n4[6 + i] = D * D / 4;
    }
    cvt_kernel<<<dim3(256, 12), 256, 0, stream>>>(ca);

    const dim3 blk(256);
    const float inv_scale = 1.0f / 32.0f; // 1/sqrt(D_OUT)

    float* out_c = (float*)d_out;                       // comp_fused [NC, D]
    float* out_p = (float*)d_out + (size_t)NC * D;      // prot_fused [NP, D]

    // --- 6 projections, one dispatch: bf16, 128x128, BK=32, gload_lds ---
    // grid (M/128, N/128, 6) = (32, 8, 6); x (M) fast -> A-sharing blocks
    // (same x) land on the same XCD (stride 32 % 8 == 0).
    {
        GemmArgs<6> ga;
        ushort_t* outs[6] = {qc, kc, vcT, qp, kp, vpT};
        const int bidx[6] = {7, 9, 11, 13, 15, 17};
        for (int i = 0; i < 6; i++) {
            ga.A[i] = xb[i];
            ga.B[i] = wb[i];
            ga.bias[i] = (const float*)d_in[bidx[i]];
            ga.C[i] = outs[i];
            ga.trans[i] = (i == 2 || i == 5);   // v projections -> transposed
        }
        gemm_bf16<128, 128, 32, 6, true, true, true, 2>
            <<<dim3(NC / 128, D / 128, 6), blk, 0, stream>>>(ga, NC, D, D, 1.0f);
    }

    // --- 2 score GEMMs, one dispatch: bf16, 128x128, BK=32, gload_lds ---
    {
        GemmArgs<2> ga;
        ga.A[0] = qc; ga.B[0] = kp; ga.C[0] = Sb1;
        ga.A[1] = qp; ga.B[1] = kc; ga.C[1] = Sb2;
        ga.bias[0] = ga.bias[1] = nullptr;
        ga.trans[0] = ga.trans[1] = 0;
        gemm_bf16<128, 128, 32, 2, true, false, false, 2>
            <<<dim3(4096 / 128, 4096 / 128, 2), blk, 0, stream>>>(
                ga, 4096, 4096, D, inv_scale);
    }

    // --- 2 softmaxes, one dispatch, in-place ---
    {
        SmArgs sa; sa.S[0] = Sb1; sa.S[1] = Sb2;
        softmax_kernel<<<dim3(4096, 2), blk, 0, stream>>>(sa);
    }

    // --- 2 PV GEMMs, one dispatch: bf16 in, fp32 out, BK=32, gload_lds ---
    {
        GemmArgs<2> ga;
        ga.A[0] = Sb1; ga.B[0] = vpT; ga.C[0] = out_c;
        ga.A[1] = Sb2; ga.B[1] = vcT; ga.C[1] = out_p;
        ga.bias[0] = ga.bias[1] = nullptr;
        ga.trans[0] = ga.trans[1] = 0;
        gemm_bf16<128, 128, 32, 2, false, false, false, 2>
            <<<dim3(4096 / 128, D / 128, 2), blk, 0, stream>>>(
                ga, 4096, D, 4096, 1.0f);
    }
}

// Round 2
// 508.118 us; speedup vs baseline: 1.1062x; 1.1062x over previous
//
#include <hip/hip_runtime.h>

typedef unsigned short ushort_t;
typedef short bf16x8 __attribute__((ext_vector_type(8)));
typedef float floatx4 __attribute__((ext_vector_type(4)));

// ---------- bf16 helpers (bit-level, RNE) ----------
__device__ __forceinline__ float bf2f(ushort_t u) {
    return __uint_as_float(((unsigned)u) << 16);
}
__device__ __forceinline__ ushort_t f2bf(float f) {
    unsigned u = __float_as_uint(f);
    unsigned rnd = 0x7fffu + ((u >> 16) & 1u);
    return (ushort_t)((u + rnd) >> 16);
}

// async global->LDS, 16B per lane; LDS dest = wave-uniform base + lane*16.
__device__ __forceinline__ void gload_lds16(const void* g, void* l) {
    __builtin_amdgcn_global_load_lds(
        (const __attribute__((address_space(1))) unsigned int*)g,
        (__attribute__((address_space(3))) unsigned int*)l,
        16, 0, 0);
}

// ---------- fp32 -> bf16 batch convert ----------
struct CvtArgs {
    const float* src[12];
    ushort_t* dst[12];
    int n4[12];
};

__global__ __launch_bounds__(256) void cvt_kernel(CvtArgs a) {
    int t = blockIdx.y;
    int n4 = a.n4[t];
    const float4* s = (const float4*)a.src[t];
    ushort_t* d = a.dst[t];
    int stride = gridDim.x * blockDim.x;
    for (int i = blockIdx.x * blockDim.x + threadIdx.x; i < n4; i += stride) {
        float4 v = s[i];
        ushort4 o;
        o.x = f2bf(v.x); o.y = f2bf(v.y); o.z = f2bf(v.z); o.w = f2bf(v.w);
        ((ushort4*)d)[i] = o;
    }
}

// ---------- 256x256-tile 8-phase bf16 GEMM: C = A[M,K] @ B[N,K]^T ----------
// 8-phase counted-vmcnt schedule (T3+T4+T5 from the technique catalog):
//   - BK=64 K-tiles, split into K-half slots of 32 cols (16 KB each).
//   - LDS: lA[4 slots], lB[4 slots] = 128 KB. Even tiles use slots 0(klo),
//     1(khi); odd tiles slots 2,3. Chunk-linear layout: chunk c of a slot
//     holds X[i*16+r][q*8..+7] with c = i*64+q*16+r -> staging dest AND
//     fragment ds_reads are lane-linear (0 bank conflicts, no swizzle).
//   - 8 waves (2M x 4N), per-wave output 128x64, acc[8][4] = 128 VGPR.
//   - Per phase: stage one half-slot (2 global_load_lds/thread), issue
//     ds_reads, s_barrier, 16 MFMA under setprio(1), s_barrier.
//   - Raw s_barrier (NOT __syncthreads: no vmcnt drain). s_waitcnt vmcnt(4)
//     only at phases 4 and 8 -> 2 half-slot stages stay in flight across
//     barriers. Slot lifetime (hand-verified):
//       stage targets a slot strictly after the post-barrier of the phase
//       that last reads its previous contents (ph3->slot0 after ph2, ph5->
//       slot1 after ph4, ph7->slot2 after ph6, ph1->slot3 after prev ph8);
//       every read covered: ph1/ph3 by prev ph8's vmcnt(4), ph5/ph7 by this
//       ph4's vmcnt(4). Tail iteration stages only khi(T-1) and drains
//       vmcnt(0) at ph4. Requires K % 64 == 0, T = K/64 even.
template<int NB> struct GemmArgs {
    const ushort_t* A[NB];
    const ushort_t* B[NB];
    const float* bias[NB];
    void* C[NB];
    int trans[NB];
};

template<int NB, bool BF16_OUT, bool HAS_BIAS, bool ALLOW_TRANS>
__global__ __launch_bounds__(512, 2) void gemm256(
    GemmArgs<NB> args, int M, int N, int K, float scale)
{
    __shared__ __align__(16) ushort_t lA[4 * 1024 * 8];   // 64 KB
    __shared__ __align__(16) ushort_t lB[4 * 1024 * 8];   // 64 KB

    const int z = blockIdx.z;
    const ushort_t* __restrict__ A = args.A[z];
    const ushort_t* __restrict__ B = args.B[z];

    const int tid  = threadIdx.x;
    const int lane = tid & 63;
    const int wave = tid >> 6;
    const int wm   = wave >> 2;        // 0..1 : 128-row half
    const int wn   = wave & 3;         // 0..3 : 64-col strip
    const int quad = lane >> 4;
    const int r16  = lane & 15;

    const int row0 = blockIdx.x * 256;  // x = M (fast) -> A-sharing same XCD
    const int col0 = blockIdx.y * 256;

    floatx4 acc[8][4] = {};

    // staging pointers: thread stages chunks c = tid and 512+tid of each slot
    const ushort_t* pA0; const ushort_t* pA1;
    const ushort_t* pB0; const ushort_t* pB1;
    {
        int c0 = tid,        i0 = c0 >> 6, q0 = (c0 >> 4) & 3, r0 = c0 & 15;
        int c1 = 512 + tid,  i1 = c1 >> 6, q1 = (c1 >> 4) & 3, r1 = c1 & 15;
        pA0 = A + (size_t)(row0 + i0 * 16 + r0) * K + q0 * 8;
        pA1 = A + (size_t)(row0 + i1 * 16 + r1) * K + q1 * 8;
        pB0 = B + (size_t)(col0 + i0 * 16 + r0) * K + q0 * 8;
        pB1 = B + (size_t)(col0 + i1 * 16 + r1) * K + q1 * 8;
    }

#define STA(SLOT) do { \
    gload_lds16(pA0, &lA[((SLOT) * 1024 + tid) * 8]); \
    gload_lds16(pA1, &lA[((SLOT) * 1024 + 512 + tid) * 8]); \
    pA0 += 32; pA1 += 32; } while (0)
#define STB(SLOT) do { \
    gload_lds16(pB0, &lB[((SLOT) * 1024 + tid) * 8]); \
    gload_lds16(pB1, &lB[((SLOT) * 1024 + 512 + tid) * 8]); \
    pB0 += 32; pB1 += 32; } while (0)

    const int aoff = wm * 512 + lane;   // chunk base for f=0 within a slot
    const int boff = wn * 256 + lane;

#define LDA4(SLOT, F0) do { \
    a0 = *(const bf16x8*)&lA[((SLOT) * 1024 + aoff + ((F0) + 0) * 64) * 8]; \
    a1 = *(const bf16x8*)&lA[((SLOT) * 1024 + aoff + ((F0) + 1) * 64) * 8]; \
    a2 = *(const bf16x8*)&lA[((SLOT) * 1024 + aoff + ((F0) + 2) * 64) * 8]; \
    a3 = *(const bf16x8*)&lA[((SLOT) * 1024 + aoff + ((F0) + 3) * 64) * 8]; } while (0)
#define LDB4(SLOT) do { \
    b0 = *(const bf16x8*)&lB[((SLOT) * 1024 + boff + 0 * 64) * 8]; \
    b1 = *(const bf16x8*)&lB[((SLOT) * 1024 + boff + 1 * 64) * 8]; \
    b2 = *(const bf16x8*)&lB[((SLOT) * 1024 + boff + 2 * 64) * 8]; \
    b3 = *(const bf16x8*)&lB[((SLOT) * 1024 + boff + 3 * 64) * 8]; } while (0)

#define MM16(F0) do { \
    __builtin_amdgcn_s_setprio(1); \
    acc[(F0)+0][0] = __builtin_amdgcn_mfma_f32_16x16x32_bf16(a0, b0, acc[(F0)+0][0], 0, 0, 0); \
    acc[(F0)+0][1] = __builtin_amdgcn_mfma_f32_16x16x32_bf16(a0, b1, acc[(F0)+0][1], 0, 0, 0); \
    acc[(F0)+0][2] = __builtin_amdgcn_mfma_f32_16x16x32_bf16(a0, b2, acc[(F0)+0][2], 0, 0, 0); \
    acc[(F0)+0][3] = __builtin_amdgcn_mfma_f32_16x16x32_bf16(a0, b3, acc[(F0)+0][3], 0, 0, 0); \
    acc[(F0)+1][0] = __builtin_amdgcn_mfma_f32_16x16x32_bf16(a1, b0, acc[(F0)+1][0], 0, 0, 0); \
    acc[(F0)+1][1] = __builtin_amdgcn_mfma_f32_16x16x32_bf16(a1, b1, acc[(F0)+1][1], 0, 0, 0); \
    acc[(F0)+1][2] = __builtin_amdgcn_mfma_f32_16x16x32_bf16(a1, b2, acc[(F0)+1][2], 0, 0, 0); \
    acc[(F0)+1][3] = __builtin_amdgcn_mfma_f32_16x16x32_bf16(a1, b3, acc[(F0)+1][3], 0, 0, 0); \
    acc[(F0)+2][0] = __builtin_amdgcn_mfma_f32_16x16x32_bf16(a2, b0, acc[(F0)+2][0], 0, 0, 0); \
    acc[(F0)+2][1] = __builtin_amdgcn_mfma_f32_16x16x32_bf16(a2, b1, acc[(F0)+2][1], 0, 0, 0); \
    acc[(F0)+2][2] = __builtin_amdgcn_mfma_f32_16x16x32_bf16(a2, b2, acc[(F0)+2][2], 0, 0, 0); \
    acc[(F0)+2][3] = __builtin_amdgcn_mfma_f32_16x16x32_bf16(a2, b3, acc[(F0)+2][3], 0, 0, 0); \
    acc[(F0)+3][0] = __builtin_amdgcn_mfma_f32_16x16x32_bf16(a3, b0, acc[(F0)+3][0], 0, 0, 0); \
    acc[(F0)+3][1] = __builtin_amdgcn_mfma_f32_16x16x32_bf16(a3, b1, acc[(F0)+3][1], 0, 0, 0); \
    acc[(F0)+3][2] = __builtin_amdgcn_mfma_f32_16x16x32_bf16(a3, b2, acc[(F0)+3][2], 0, 0, 0); \
    acc[(F0)+3][3] = __builtin_amdgcn_mfma_f32_16x16x32_bf16(a3, b3, acc[(F0)+3][3], 0, 0, 0); \
    __builtin_amdgcn_s_setprio(0); } while (0)

#define BAR() __builtin_amdgcn_s_barrier()
#define VMW(n) asm volatile("s_waitcnt vmcnt(" #n ")" ::: "memory")

    const int T = K / 64;       // K-tiles (even, >= 2)
    const int NIT = T / 2;

    // prologue: klo(0)->slot0, khi(0)->slot1, klo(1)->slot2  (12 loads/thread)
    STA(0); STB(0); STA(1); STB(1); STA(2); STB(2);
    VMW(4);                     // klo(0)+khi(0) landed; klo(1) in flight
    BAR();

    bf16x8 a0, a1, a2, a3, b0, b1, b2, b3;

    for (int it = 0; it < NIT; it++) {
        const bool nl = (it + 1 < NIT);
        // ph1: tile t ks0 mg0 | stage A-khi(t+1)->slot3
        STA(3);
        LDB4(0); LDA4(0, 0);
        BAR(); MM16(0); BAR();
        // ph2: tile t ks0 mg1 | stage B-khi(t+1)->slot3
        STB(3);
        LDA4(0, 4);
        BAR(); MM16(4); BAR();
        // ph3: tile t ks1 mg0 | stage A-klo(t+2)->slot0 (freed at ph2)
        if (nl) STA(0);
        LDB4(1); LDA4(1, 0);
        BAR(); MM16(0); BAR();
        // ph4: tile t ks1 mg1 | stage B-klo(t+2)->slot0 | counted wait
        if (nl) STB(0);
        LDA4(1, 4);
        if (nl) { VMW(4); } else { VMW(0); }
        BAR(); MM16(4); BAR();
        // ph5: tile t+1 ks0 mg0 | stage A-khi(t+2)->slot1 (freed at ph4)
        if (nl) STA(1);
        LDB4(2); LDA4(2, 0);
        BAR(); MM16(0); BAR();
        // ph6: tile t+1 ks0 mg1 | stage B-khi(t+2)->slot1
        if (nl) STB(1);
        LDA4(2, 4);
        BAR(); MM16(4); BAR();
        // ph7: tile t+1 ks1 mg0 | stage A-klo(t+3)->slot2 (freed at ph6)
        if (nl) STA(2);
        LDB4(3); LDA4(3, 0);
        BAR(); MM16(0); BAR();
        // ph8: tile t+1 ks1 mg1 | stage B-klo(t+3)->slot2 | counted wait
        if (nl) STB(2);
        LDA4(3, 4);
        if (nl) VMW(4);
        BAR(); MM16(4); BAR();
    }

#undef STA
#undef STB
#undef LDA4
#undef LDB4
#undef MM16
#undef BAR
#undef VMW

    // ---------------- epilogue ----------------
    float bv[4];
    if (HAS_BIAS) {
        #pragma unroll
        for (int j = 0; j < 4; j++)
            bv[j] = args.bias[z][col0 + (wn * 4 + j) * 16 + r16];
    }

    void* C = args.C[z];
    const bool do_trans = ALLOW_TRANS && args.trans[z];

    #pragma unroll
    for (int i = 0; i < 8; i++) {
        const int m_base = row0 + (wm * 8 + i) * 16 + quad * 4;
        #pragma unroll
        for (int j = 0; j < 4; j++) {
            const int n = col0 + (wn * 4 + j) * 16 + r16;
            if (ALLOW_TRANS && do_trans) {
                // C^T layout [N][M], bf16; 4 consecutive m -> one 8B store
                ushort4 o;
                float v0 = acc[i][j][0] * scale; if (HAS_BIAS) v0 += bv[j];
                float v1 = acc[i][j][1] * scale; if (HAS_BIAS) v1 += bv[j];
                float v2 = acc[i][j][2] * scale; if (HAS_BIAS) v2 += bv[j];
                float v3 = acc[i][j][3] * scale; if (HAS_BIAS) v3 += bv[j];
                o.x = f2bf(v0); o.y = f2bf(v1); o.z = f2bf(v2); o.w = f2bf(v3);
                *(ushort4*)((ushort_t*)C + (size_t)n * M + m_base) = o;
            } else {
                #pragma unroll
                for (int r = 0; r < 4; r++) {
                    float v = acc[i][j][r] * scale;
                    if (HAS_BIAS) v += bv[j];
                    size_t off = (size_t)(m_base + r) * N + n;
                    if (BF16_OUT) ((ushort_t*)C)[off] = f2bf(v);
                    else          ((float*)C)[off] = v;
                }
            }
        }
    }
}

// ---------- row softmax, in-place: S[row,0..4095] bf16, fp32 math ----------
struct SmArgs { ushort_t* S[2]; };

__global__ __launch_bounds__(256) void softmax_kernel(SmArgs a) {
    const int N = 4096;
    ushort_t* S = a.S[blockIdx.y];
    const int row = blockIdx.x;
    const int tid = threadIdx.x;
    const int lane = tid & 63;
    const int wave = tid >> 6;

    bf16x8* ptr = (bf16x8*)(S + (size_t)row * N);
    bf16x8 c0 = ptr[2 * tid];
    bf16x8 c1 = ptr[2 * tid + 1];

    float x[16];
    #pragma unroll
    for (int k = 0; k < 8; k++) {
        x[k]     = bf2f((ushort_t)c0[k]);
        x[8 + k] = bf2f((ushort_t)c1[k]);
    }

    float m = -3.4e38f;
    #pragma unroll
    for (int k = 0; k < 16; k++) m = fmaxf(m, x[k]);
    #pragma unroll
    for (int off = 32; off > 0; off >>= 1) m = fmaxf(m, __shfl_xor(m, off));

    __shared__ float redmax[4], redsum[4];
    if (lane == 0) redmax[wave] = m;
    __syncthreads();
    m = fmaxf(fmaxf(redmax[0], redmax[1]), fmaxf(redmax[2], redmax[3]));

    float s = 0.f;
    #pragma unroll
    for (int k = 0; k < 16; k++) { x[k] = __expf(x[k] - m); s += x[k]; }
    #pragma unroll
    for (int off = 32; off > 0; off >>= 1) s += __shfl_xor(s, off);
    if (lane == 0) redsum[wave] = s;
    __syncthreads();
    s = redsum[0] + redsum[1] + redsum[2] + redsum[3];
    const float inv = 1.0f / s;

    bf16x8 o0, o1;
    #pragma unroll
    for (int k = 0; k < 8; k++) {
        o0[k] = (short)f2bf(x[k] * inv);
        o1[k] = (short)f2bf(x[8 + k] * inv);
    }
    ptr[2 * tid]     = o0;
    ptr[2 * tid + 1] = o1;
}

// ---------- launch ----------
extern "C" void kernel_launch(void* const* d_in, const int* in_sizes, int n_in,
                              void* d_out, int out_size, void* d_ws, size_t ws_size,
                              hipStream_t stream) {
    (void)in_sizes; (void)n_in; (void)out_size;
    const int NC = 4096, NP = 4096, D = 1024;

    char* ws = (char*)d_ws;
    size_t off = 0;
    auto alloc = [&](size_t b) { size_t o = off; off += (b + 255) & ~(size_t)255; return o; };

    ushort_t* xb[6];
    for (int i = 0; i < 6; i++) xb[i] = (ushort_t*)(ws + alloc((size_t)NC * D * 2));
    ushort_t* wb[6];
    for (int i = 0; i < 6; i++) wb[i] = (ushort_t*)(ws + alloc((size_t)D * D * 2));
    ushort_t* qc  = (ushort_t*)(ws + alloc((size_t)NC * D * 2));
    ushort_t* kc  = (ushort_t*)(ws + alloc((size_t)NC * D * 2));
    ushort_t* qp  = (ushort_t*)(ws + alloc((size_t)NP * D * 2));
    ushort_t* kp  = (ushort_t*)(ws + alloc((size_t)NP * D * 2));
    ushort_t* vcT = (ushort_t*)(ws + alloc((size_t)NC * D * 2)); // [D][NC]
    ushort_t* vpT = (ushort_t*)(ws + alloc((size_t)NP * D * 2)); // [D][NP]
    ushort_t* Sb1 = (ushort_t*)(ws + alloc((size_t)4096 * 4096 * 2));
    ushort_t* Sb2 = (ushort_t*)(ws + alloc((size_t)4096 * 4096 * 2));

    if (ws_size < off) return;

    // convert inputs + weights to bf16 (one dispatch)
    CvtArgs ca;
    for (int i = 0; i < 6; i++) {
        ca.src[i] = (const float*)d_in[i];
        ca.dst[i] = xb[i];
        ca.n4[i] = NC * D / 4;
    }
    const int widx[6] = {6, 8, 10, 12, 14, 16};
    for (int i = 0; i < 6; i++) {
        ca.src[6 + i] = (const float*)d_in[widx[i]];
        ca.dst[6 + i] = wb[i];
        ca.n4[6 + i] = D * D / 4;
    }
    cvt_kernel<<<dim3(256, 12), 256, 0, stream>>>(ca);

    const dim3 blk(512);
    const float inv_scale = 1.0f / 32.0f; // 1/sqrt(D_OUT)

    float* out_c = (float*)d_out;                       // comp_fused [NC, D]
    float* out_p = (float*)d_out + (size_t)NC * D;      // prot_fused [NP, D]

    // --- 6 projections, one dispatch: 256^2 8-phase, K=1024 ---
    {
        GemmArgs<6> ga;
        ushort_t* outs[6] = {qc, kc, vcT, qp, kp, vpT};
        const int bidx[6] = {7, 9, 11, 13, 15, 17};
        for (int i = 0; i < 6; i++) {
            ga.A[i] = xb[i];
            ga.B[i] = wb[i];
            ga.bias[i] = (const float*)d_in[bidx[i]];
            ga.C[i] = outs[i];
            ga.trans[i] = (i == 2 || i == 5);   // v projections -> transposed
        }
        gemm256<6, true, true, true>
            <<<dim3(NC / 256, D / 256, 6), blk, 0, stream>>>(ga, NC, D, D, 1.0f);
    }

    // --- 2 score GEMMs, one dispatch: 256^2 8-phase, K=1024 ---
    {
        GemmArgs<2> ga;
        ga.A[0] = qc; ga.B[0] = kp; ga.C[0] = Sb1;
        ga.A[1] = qp; ga.B[1] = kc; ga.C[1] = Sb2;
        ga.bias[0] = ga.bias[1] = nullptr;
        ga.trans[0] = ga.trans[1] = 0;
        gemm256<2, true, false, false>
            <<<dim3(4096 / 256, 4096 / 256, 2), blk, 0, stream>>>(
                ga, 4096, 4096, D, inv_scale);
    }

    // --- 2 softmaxes, one dispatch, in-place ---
    {
        SmArgs sa; sa.S[0] = Sb1; sa.S[1] = Sb2;
        softmax_kernel<<<dim3(4096, 2), dim3(256), 0, stream>>>(sa);
    }

    // --- 2 PV GEMMs, one dispatch: 256^2 8-phase, K=4096, fp32 out ---
    {
        GemmArgs<2> ga;
        ga.A[0] = Sb1; ga.B[0] = vpT; ga.C[0] = out_c;
        ga.A[1] = Sb2; ga.B[1] = vcT; ga.C[1] = out_p;
        ga.bias[0] = ga.bias[1] = nullptr;
        ga.trans[0] = ga.trans[1] = 0;
        gemm256<2, false, false, false>
            <<<dim3(4096 / 256, D / 256, 2), blk, 0, stream>>>(
                ga, 4096, D, 4096, 1.0f);
    }
}

// Round 3
// 506.670 us; speedup vs baseline: 1.1094x; 1.0029x over previous
//
#include <hip/hip_runtime.h>

typedef unsigned short ushort_t;
typedef short bf16x8 __attribute__((ext_vector_type(8)));
typedef float floatx4 __attribute__((ext_vector_type(4)));

// ---------- bf16 helpers (bit-level, RNE) ----------
__device__ __forceinline__ float bf2f(ushort_t u) {
    return __uint_as_float(((unsigned)u) << 16);
}
__device__ __forceinline__ ushort_t f2bf(float f) {
    unsigned u = __float_as_uint(f);
    unsigned rnd = 0x7fffu + ((u >> 16) & 1u);
    return (ushort_t)((u + rnd) >> 16);
}

// async global->LDS, 16B per lane; LDS dest = wave-uniform base + lane*16.
__device__ __forceinline__ void gload_lds16(const void* g, void* l) {
    __builtin_amdgcn_global_load_lds(
        (const __attribute__((address_space(1))) unsigned int*)g,
        (__attribute__((address_space(3))) unsigned int*)l,
        16, 0, 0);
}

// ---------- fp32 -> bf16 batch convert ----------
struct CvtArgs {
    const float* src[12];
    ushort_t* dst[12];
    int n4[12];
};

__global__ __launch_bounds__(256) void cvt_kernel(CvtArgs a) {
    int t = blockIdx.y;
    int n4 = a.n4[t];
    const float4* s = (const float4*)a.src[t];
    ushort_t* d = a.dst[t];
    int stride = gridDim.x * blockDim.x;
    for (int i = blockIdx.x * blockDim.x + threadIdx.x; i < n4; i += stride) {
        float4 v = s[i];
        ushort4 o;
        o.x = f2bf(v.x); o.y = f2bf(v.y); o.z = f2bf(v.z); o.w = f2bf(v.w);
        ((ushort4*)d)[i] = o;
    }
}

// ---------- 256xBN-tile 8-phase bf16 GEMM: C = A[M,K] @ B[N,K]^T ----------
// 8-phase counted-vmcnt schedule (T3+T4+T5). BM=256 fixed; BN = MJ*64
// (MJ=4 -> 256 wide, MJ=2 -> 128 wide for narrow-N / occupancy balance).
//   - BK=64 K-tiles split into K-half slots of 32 cols. A slot = 16 KB,
//     B slot = BN*32*2 B. LDS = 64 KB + BN/2 KB*... (MJ=4: 128 KB, 1 blk/CU;
//     MJ=2: 96 KB, 1 blk/CU).
//   - Chunk-linear layout: chunk c = i*64 + q*16 + r holds X[i*16+r][q*8..+7];
//     staging dest and fragment ds_reads are lane-linear (0 bank conflicts).
//   - 8 waves (2M x 4N): per-wave output 128 x (BN/4), acc[8][MJ].
//   - Per phase: stage one half-slot (A: 2 loads/thread, B: CB=MJ/2 loads),
//     issue ds_reads, s_barrier, 4*MJ MFMA under setprio(1), s_barrier.
//   - Raw s_barrier (no vmcnt drain). Counted s_waitcnt vmcnt(2+CB) only at
//     phases 4 and 8 -> two half-slot stages stay in flight across barriers.
//     Slot lifetime: stage targets a slot strictly after the post-barrier of
//     the phase that last reads its previous contents; every read covered by
//     the in-order vmcnt wait two phases earlier. Tail drains vmcnt(0) at ph4.
//   - Requires K % 128 == 0 (T = K/64 even).
template<int NB> struct GemmArgs {
    const ushort_t* A[NB];
    const ushort_t* B[NB];
    const float* bias[NB];
    void* C[NB];
    int trans[NB];
};

template<int NB, int MJ, bool BF16_OUT, bool HAS_BIAS, bool ALLOW_TRANS>
__global__ __launch_bounds__(512, 2) void gemm256(
    GemmArgs<NB> args, int M, int N, int K, float scale)
{
    constexpr int BN = MJ * 64;        // tile width
    constexpr int CB = MJ / 2;         // B staging chunks per thread (1 or 2)
    constexpr int BCH = BN * 4;        // chunks per B slot

    __shared__ __align__(16) ushort_t lA[4 * 1024 * 8];     // 64 KB
    __shared__ __align__(16) ushort_t lB[4 * BN * 32];      // 4 slots

    const int z = blockIdx.z;
    const ushort_t* __restrict__ A = args.A[z];
    const ushort_t* __restrict__ B = args.B[z];

    const int tid  = threadIdx.x;
    const int lane = tid & 63;
    const int wave = tid >> 6;
    const int wm   = wave >> 2;        // 0..1 : 128-row half
    const int wn   = wave & 3;         // 0..3 : (BN/4)-col strip
    const int quad = lane >> 4;
    const int r16  = lane & 15;

    const int row0 = blockIdx.x * 256;  // x = M (fast) -> A-sharing same XCD
    const int col0 = blockIdx.y * BN;

    floatx4 acc[8][MJ] = {};

    // staging pointers
    const ushort_t* pA0; const ushort_t* pA1;
    const ushort_t* pB[CB];
    {
        int c0 = tid,        i0 = c0 >> 6, q0 = (c0 >> 4) & 3, r0 = c0 & 15;
        int c1 = 512 + tid,  i1 = c1 >> 6, q1 = (c1 >> 4) & 3, r1 = c1 & 15;
        pA0 = A + (size_t)(row0 + i0 * 16 + r0) * K + q0 * 8;
        pA1 = A + (size_t)(row0 + i1 * 16 + r1) * K + q1 * 8;
        #pragma unroll
        for (int c = 0; c < CB; c++) {
            int cc = c * 512 + tid, ii = cc >> 6, qq = (cc >> 4) & 3, rr = cc & 15;
            pB[c] = B + (size_t)(col0 + ii * 16 + rr) * K + qq * 8;
        }
    }

    auto STA = [&](int slot) {
        gload_lds16(pA0, &lA[(slot * 1024 + tid) * 8]);
        gload_lds16(pA1, &lA[(slot * 1024 + 512 + tid) * 8]);
        pA0 += 32; pA1 += 32;
    };
    auto STB = [&](int slot) {
        #pragma unroll
        for (int c = 0; c < CB; c++) {
            gload_lds16(pB[c], &lB[(slot * BCH + c * 512 + tid) * 8]);
            pB[c] += 32;
        }
    };

    const int aoff = wm * 512 + lane;   // chunk base within an A slot
    const int boff = wn * MJ * 64 + lane;

    bf16x8 af[4], bfr[MJ];

    auto LDA = [&](int slot, int f0) {
        #pragma unroll
        for (int i2 = 0; i2 < 4; i2++)
            af[i2] = *(const bf16x8*)&lA[(slot * 1024 + aoff + (f0 + i2) * 64) * 8];
    };
    auto LDB = [&](int slot) {
        #pragma unroll
        for (int j = 0; j < MJ; j++)
            bfr[j] = *(const bf16x8*)&lB[(slot * BCH + boff + j * 64) * 8];
    };

#define MM(F0) do { \
    __builtin_amdgcn_s_setprio(1); \
    _Pragma("unroll") \
    for (int i2 = 0; i2 < 4; i2++) { \
        _Pragma("unroll") \
        for (int j = 0; j < MJ; j++) \
            acc[(F0) + i2][j] = __builtin_amdgcn_mfma_f32_16x16x32_bf16( \
                af[i2], bfr[j], acc[(F0) + i2][j], 0, 0, 0); \
    } \
    __builtin_amdgcn_s_setprio(0); } while (0)

#define BAR() __builtin_amdgcn_s_barrier()
    // counted wait: leave the 2 most recent half-slot stages (2+CB loads) in flight
#define VMWS() do { \
    if constexpr (CB == 2) asm volatile("s_waitcnt vmcnt(4)" ::: "memory"); \
    else                   asm volatile("s_waitcnt vmcnt(3)" ::: "memory"); } while (0)
#define VMW0() asm volatile("s_waitcnt vmcnt(0)" ::: "memory")

    const int T = K / 64;       // K-tiles (even)
    const int NIT = T / 2;

    // prologue: klo(0)->slot0, khi(0)->slot1, klo(1)->slot2
    STA(0); STB(0); STA(1); STB(1); STA(2); STB(2);
    VMWS();                     // slot0 + slot1 landed; slot2 in flight
    BAR();

    for (int it = 0; it < NIT; it++) {
        const bool nl = (it + 1 < NIT);
        // ph1: tile t ks0 mg0 | stage A-khi(t+1)->slot3
        STA(3);
        LDB(0); LDA(0, 0);
        BAR(); MM(0); BAR();
        // ph2: tile t ks0 mg1 | stage B-khi(t+1)->slot3
        STB(3);
        LDA(0, 4);
        BAR(); MM(4); BAR();
        // ph3: tile t ks1 mg0 | stage A-klo(t+2)->slot0 (freed at ph2)
        if (nl) STA(0);
        LDB(1); LDA(1, 0);
        BAR(); MM(0); BAR();
        // ph4: tile t ks1 mg1 | stage B-klo(t+2)->slot0 | counted wait
        if (nl) STB(0);
        LDA(1, 4);
        if (nl) { VMWS(); } else { VMW0(); }
        BAR(); MM(4); BAR();
        // ph5: tile t+1 ks0 mg0 | stage A-khi(t+2)->slot1 (freed at ph4)
        if (nl) STA(1);
        LDB(2); LDA(2, 0);
        BAR(); MM(0); BAR();
        // ph6: tile t+1 ks0 mg1 | stage B-khi(t+2)->slot1
        if (nl) STB(1);
        LDA(2, 4);
        BAR(); MM(4); BAR();
        // ph7: tile t+1 ks1 mg0 | stage A-klo(t+3)->slot2 (freed at ph6)
        if (nl) STA(2);
        LDB(3); LDA(3, 0);
        BAR(); MM(0); BAR();
        // ph8: tile t+1 ks1 mg1 | stage B-klo(t+3)->slot2 | counted wait
        if (nl) STB(2);
        LDA(3, 4);
        if (nl) VMWS();
        BAR(); MM(4); BAR();
    }

#undef MM
#undef BAR
#undef VMWS
#undef VMW0

    // ---------------- epilogue ----------------
    float bv[MJ];
    if (HAS_BIAS) {
        #pragma unroll
        for (int j = 0; j < MJ; j++)
            bv[j] = args.bias[z][col0 + (wn * MJ + j) * 16 + r16];
    }

    void* C = args.C[z];
    const bool do_trans = ALLOW_TRANS && args.trans[z];

    #pragma unroll
    for (int i = 0; i < 8; i++) {
        const int m_base = row0 + (wm * 8 + i) * 16 + quad * 4;
        #pragma unroll
        for (int j = 0; j < MJ; j++) {
            const int n = col0 + (wn * MJ + j) * 16 + r16;
            if (ALLOW_TRANS && do_trans) {
                // C^T layout [N][M], bf16; 4 consecutive m -> one 8B store
                ushort4 o;
                float v0 = acc[i][j][0] * scale; if (HAS_BIAS) v0 += bv[j];
                float v1 = acc[i][j][1] * scale; if (HAS_BIAS) v1 += bv[j];
                float v2 = acc[i][j][2] * scale; if (HAS_BIAS) v2 += bv[j];
                float v3 = acc[i][j][3] * scale; if (HAS_BIAS) v3 += bv[j];
                o.x = f2bf(v0); o.y = f2bf(v1); o.z = f2bf(v2); o.w = f2bf(v3);
                *(ushort4*)((ushort_t*)C + (size_t)n * M + m_base) = o;
            } else {
                #pragma unroll
                for (int r = 0; r < 4; r++) {
                    float v = acc[i][j][r] * scale;
                    if (HAS_BIAS) v += bv[j];
                    size_t off = (size_t)(m_base + r) * N + n;
                    if (BF16_OUT) ((ushort_t*)C)[off] = f2bf(v);
                    else          ((float*)C)[off] = v;
                }
            }
        }
    }
}

// ---------- row softmax, in-place: S[row,0..4095] bf16, fp32 math ----------
struct SmArgs { ushort_t* S[2]; };

__global__ __launch_bounds__(256) void softmax_kernel(SmArgs a) {
    const int N = 4096;
    ushort_t* S = a.S[blockIdx.y];
    const int row = blockIdx.x;
    const int tid = threadIdx.x;
    const int lane = tid & 63;
    const int wave = tid >> 6;

    bf16x8* ptr = (bf16x8*)(S + (size_t)row * N);
    bf16x8 c0 = ptr[2 * tid];
    bf16x8 c1 = ptr[2 * tid + 1];

    float x[16];
    #pragma unroll
    for (int k = 0; k < 8; k++) {
        x[k]     = bf2f((ushort_t)c0[k]);
        x[8 + k] = bf2f((ushort_t)c1[k]);
    }

    float m = -3.4e38f;
    #pragma unroll
    for (int k = 0; k < 16; k++) m = fmaxf(m, x[k]);
    #pragma unroll
    for (int off = 32; off > 0; off >>= 1) m = fmaxf(m, __shfl_xor(m, off));

    __shared__ float redmax[4], redsum[4];
    if (lane == 0) redmax[wave] = m;
    __syncthreads();
    m = fmaxf(fmaxf(redmax[0], redmax[1]), fmaxf(redmax[2], redmax[3]));

    float s = 0.f;
    #pragma unroll
    for (int k = 0; k < 16; k++) { x[k] = __expf(x[k] - m); s += x[k]; }
    #pragma unroll
    for (int off = 32; off > 0; off >>= 1) s += __shfl_xor(s, off);
    if (lane == 0) redsum[wave] = s;
    __syncthreads();
    s = redsum[0] + redsum[1] + redsum[2] + redsum[3];
    const float inv = 1.0f / s;

    bf16x8 o0, o1;
    #pragma unroll
    for (int k = 0; k < 8; k++) {
        o0[k] = (short)f2bf(x[k] * inv);
        o1[k] = (short)f2bf(x[8 + k] * inv);
    }
    ptr[2 * tid]     = o0;
    ptr[2 * tid + 1] = o1;
}

// ---------- launch ----------
extern "C" void kernel_launch(void* const* d_in, const int* in_sizes, int n_in,
                              void* d_out, int out_size, void* d_ws, size_t ws_size,
                              hipStream_t stream) {
    (void)in_sizes; (void)n_in; (void)out_size;
    const int NC = 4096, NP = 4096, D = 1024;

    char* ws = (char*)d_ws;
    size_t off = 0;
    auto alloc = [&](size_t b) { size_t o = off; off += (b + 255) & ~(size_t)255; return o; };

    ushort_t* xb[6];
    for (int i = 0; i < 6; i++) xb[i] = (ushort_t*)(ws + alloc((size_t)NC * D * 2));
    ushort_t* wb[6];
    for (int i = 0; i < 6; i++) wb[i] = (ushort_t*)(ws + alloc((size_t)D * D * 2));
    ushort_t* qc  = (ushort_t*)(ws + alloc((size_t)NC * D * 2));
    ushort_t* kc  = (ushort_t*)(ws + alloc((size_t)NC * D * 2));
    ushort_t* qp  = (ushort_t*)(ws + alloc((size_t)NP * D * 2));
    ushort_t* kp  = (ushort_t*)(ws + alloc((size_t)NP * D * 2));
    ushort_t* vcT = (ushort_t*)(ws + alloc((size_t)NC * D * 2)); // [D][NC]
    ushort_t* vpT = (ushort_t*)(ws + alloc((size_t)NP * D * 2)); // [D][NP]
    ushort_t* Sb1 = (ushort_t*)(ws + alloc((size_t)4096 * 4096 * 2));
    ushort_t* Sb2 = (ushort_t*)(ws + alloc((size_t)4096 * 4096 * 2));

    if (ws_size < off) return;

    // convert inputs + weights to bf16 (one dispatch)
    CvtArgs ca;
    for (int i = 0; i < 6; i++) {
        ca.src[i] = (const float*)d_in[i];
        ca.dst[i] = xb[i];
        ca.n4[i] = NC * D / 4;
    }
    const int widx[6] = {6, 8, 10, 12, 14, 16};
    for (int i = 0; i < 6; i++) {
        ca.src[6 + i] = (const float*)d_in[widx[i]];
        ca.dst[6 + i] = wb[i];
        ca.n4[6 + i] = D * D / 4;
    }
    cvt_kernel<<<dim3(256, 12), 256, 0, stream>>>(ca);

    const dim3 blk(512);
    const float inv_scale = 1.0f / 32.0f; // 1/sqrt(D_OUT)

    float* out_c = (float*)d_out;                       // comp_fused [NC, D]
    float* out_p = (float*)d_out + (size_t)NC * D;      // prot_fused [NP, D]

    // --- 6 projections: 256x128 8-phase, K=1024; grid 768 = 3 blocks/CU ---
    {
        GemmArgs<6> ga;
        ushort_t* outs[6] = {qc, kc, vcT, qp, kp, vpT};
        const int bidx[6] = {7, 9, 11, 13, 15, 17};
        for (int i = 0; i < 6; i++) {
            ga.A[i] = xb[i];
            ga.B[i] = wb[i];
            ga.bias[i] = (const float*)d_in[bidx[i]];
            ga.C[i] = outs[i];
            ga.trans[i] = (i == 2 || i == 5);   // v projections -> transposed
        }
        gemm256<6, 2, true, true, true>
            <<<dim3(NC / 256, D / 128, 6), blk, 0, stream>>>(ga, NC, D, D, 1.0f);
    }

    // --- 2 score GEMMs: 256x256 8-phase, K=1024; grid 512 = 2 blocks/CU ---
    {
        GemmArgs<2> ga;
        ga.A[0] = qc; ga.B[0] = kp; ga.C[0] = Sb1;
        ga.A[1] = qp; ga.B[1] = kc; ga.C[1] = Sb2;
        ga.bias[0] = ga.bias[1] = nullptr;
        ga.trans[0] = ga.trans[1] = 0;
        gemm256<2, 4, true, false, false>
            <<<dim3(4096 / 256, 4096 / 256, 2), blk, 0, stream>>>(
                ga, 4096, 4096, D, inv_scale);
    }

    // --- 2 softmaxes, one dispatch, in-place ---
    {
        SmArgs sa; sa.S[0] = Sb1; sa.S[1] = Sb2;
        softmax_kernel<<<dim3(4096, 2), dim3(256), 0, stream>>>(sa);
    }

    // --- 2 PV GEMMs: 256x128 8-phase, K=4096, fp32 out; grid 256 = 1/CU ---
    {
        GemmArgs<2> ga;
        ga.A[0] = Sb1; ga.B[0] = vpT; ga.C[0] = out_c;
        ga.A[1] = Sb2; ga.B[1] = vcT; ga.C[1] = out_p;
        ga.bias[0] = ga.bias[1] = nullptr;
        ga.trans[0] = ga.trans[1] = 0;
        gemm256<2, 2, false, false, false>
            <<<dim3(4096 / 256, D / 128, 2), blk, 0, stream>>>(
                ga, 4096, D, 4096, 1.0f);
    }
}

// Round 4
// 469.064 us; speedup vs baseline: 1.1983x; 1.0802x over previous
//
#include <hip/hip_runtime.h>

typedef unsigned short ushort_t;
typedef short bf16x8 __attribute__((ext_vector_type(8)));
typedef float floatx4 __attribute__((ext_vector_type(4)));

// ---------- bf16 helpers (bit-level, RNE) ----------
__device__ __forceinline__ float bf2f(ushort_t u) {
    return __uint_as_float(((unsigned)u) << 16);
}
__device__ __forceinline__ ushort_t f2bf(float f) {
    unsigned u = __float_as_uint(f);
    unsigned rnd = 0x7fffu + ((u >> 16) & 1u);
    return (ushort_t)((u + rnd) >> 16);
}

// async global->LDS, 16B per lane; LDS dest = wave-uniform base + lane*16.
__device__ __forceinline__ void gload_lds16(const void* g, void* l) {
    __builtin_amdgcn_global_load_lds(
        (const __attribute__((address_space(1))) unsigned int*)g,
        (__attribute__((address_space(3))) unsigned int*)l,
        16, 0, 0);
}

// ---------- fp32 -> bf16 batch convert ----------
struct CvtArgs {
    const float* src[12];
    ushort_t* dst[12];
    int n4[12];
};

__global__ __launch_bounds__(256) void cvt_kernel(CvtArgs a) {
    int t = blockIdx.y;
    int n4 = a.n4[t];
    const float4* s = (const float4*)a.src[t];
    ushort_t* d = a.dst[t];
    int stride = gridDim.x * blockDim.x;
    for (int i = blockIdx.x * blockDim.x + threadIdx.x; i < n4; i += stride) {
        float4 v = s[i];
        ushort4 o;
        o.x = f2bf(v.x); o.y = f2bf(v.y); o.z = f2bf(v.z); o.w = f2bf(v.w);
        ((ushort4*)d)[i] = o;
    }
}

// ---------- fp32 elementwise add: out += part ----------
__global__ __launch_bounds__(256) void add_kernel(float* out, const float* part, int n4) {
    int stride = gridDim.x * blockDim.x;
    for (int i = blockIdx.x * blockDim.x + threadIdx.x; i < n4; i += stride) {
        float4 o = ((float4*)out)[i];
        float4 p = ((const float4*)part)[i];
        o.x += p.x; o.y += p.y; o.z += p.z; o.w += p.w;
        ((float4*)out)[i] = o;
    }
}

// ---------- 256xBN-tile 8-phase bf16 GEMM: C = A[M,K] @ B[N,K]^T ----------
// 8-phase counted-vmcnt schedule (T3+T4+T5), with ds_read/MFMA OVERLAP:
// fragment registers are double-buffered (set a/b); phase p's MM consumes
// the set loaded in phase p-1, and issues the ds_reads for phase p+1 after
// its MFMAs (inside the same barrier pair) -> LDS reads complete under the
// other waves' MFMA drain instead of serially extending the phase.
//   - BK=64 K-tiles split into K-half slots of 32 cols. A slot = 16 KB,
//     B slot = BN*32*2 B. LDS: MJ=4 -> 128 KB, MJ=2 -> 96 KB (1 block/CU).
//   - Chunk-linear layout: chunk c = i*64 + q*16 + r holds X[i*16+r][q*8..+7];
//     staging dest and fragment ds_reads are lane-linear (0 bank conflicts).
//   - 8 waves (2M x 4N): per-wave output 128 x (BN/4), acc[8][MJ].
//   - Raw s_barrier (no vmcnt drain). Counted s_waitcnt vmcnt(2+CB) only at
//     phases 4 and 8 -> two half-slot stages in flight across barriers.
//     Slot lifetime (re-derived for the overlapped reads): reads of slot s
//     at phase p are covered by the in-order vmcnt wait (slot2 read at ph4-end
//     is covered by ph4's VMWS; slot0/1/3 reads are >=3 phases after staging);
//     stages overwrite slots last read >=2 barriers earlier. Tail iteration
//     drains vmcnt(0) at ph4; its trailing LD reads stale-but-valid LDS that
//     feeds no MM.
//   - split-K support: per-z koff column offset, ldk = row stride, K = loop
//     extent. Requires K % 128 == 0.
template<int NB> struct GemmArgs {
    const ushort_t* A[NB];
    const ushort_t* B[NB];
    const float* bias[NB];
    void* C[NB];
    int trans[NB];
    int koff[NB];
};

template<int NB, int MJ, bool BF16_OUT, bool HAS_BIAS, bool ALLOW_TRANS>
__global__ __launch_bounds__(512, 2) void gemm256(
    GemmArgs<NB> args, int M, int N, int K, int ldk, float scale)
{
    constexpr int BN = MJ * 64;        // tile width
    constexpr int CB = MJ / 2;         // B staging chunks per thread (1 or 2)
    constexpr int BCH = BN * 4;        // chunks per B slot

    __shared__ __align__(16) ushort_t lA[4 * 1024 * 8];     // 64 KB
    __shared__ __align__(16) ushort_t lB[4 * BN * 32];      // 4 slots

    const int z = blockIdx.z;
    const ushort_t* __restrict__ A = args.A[z] + args.koff[z];
    const ushort_t* __restrict__ B = args.B[z] + args.koff[z];

    const int tid  = threadIdx.x;
    const int lane = tid & 63;
    const int wave = tid >> 6;
    const int wm   = wave >> 2;        // 0..1 : 128-row half
    const int wn   = wave & 3;         // 0..3 : (BN/4)-col strip
    const int quad = lane >> 4;
    const int r16  = lane & 15;

    const int row0 = blockIdx.x * 256;  // x = M (fast) -> A-sharing same XCD
    const int col0 = blockIdx.y * BN;

    floatx4 acc[8][MJ] = {};

    // staging pointers
    const ushort_t* pA0; const ushort_t* pA1;
    const ushort_t* pB[CB];
    {
        int c0 = tid,        i0 = c0 >> 6, q0 = (c0 >> 4) & 3, r0 = c0 & 15;
        int c1 = 512 + tid,  i1 = c1 >> 6, q1 = (c1 >> 4) & 3, r1 = c1 & 15;
        pA0 = A + (size_t)(row0 + i0 * 16 + r0) * ldk + q0 * 8;
        pA1 = A + (size_t)(row0 + i1 * 16 + r1) * ldk + q1 * 8;
        #pragma unroll
        for (int c = 0; c < CB; c++) {
            int cc = c * 512 + tid, ii = cc >> 6, qq = (cc >> 4) & 3, rr = cc & 15;
            pB[c] = B + (size_t)(col0 + ii * 16 + rr) * ldk + qq * 8;
        }
    }

    auto STA = [&](int slot) {
        gload_lds16(pA0, &lA[(slot * 1024 + tid) * 8]);
        gload_lds16(pA1, &lA[(slot * 1024 + 512 + tid) * 8]);
        pA0 += 32; pA1 += 32;
    };
    auto STB = [&](int slot) {
        #pragma unroll
        for (int c = 0; c < CB; c++) {
            gload_lds16(pB[c], &lB[(slot * BCH + c * 512 + tid) * 8]);
            pB[c] += 32;
        }
    };

    const int aoff = wm * 512 + lane;   // chunk base within an A slot
    const int boff = wn * MJ * 64 + lane;

    // double-buffered fragment register sets
    bf16x8 af_a[4], bfr_a[MJ], af_b[4], bfr_b[MJ];

    auto LD = [&](bf16x8 (&af)[4], bf16x8 (&bfr)[MJ], int slot, int f0) {
        #pragma unroll
        for (int j = 0; j < MJ; j++)
            bfr[j] = *(const bf16x8*)&lB[(slot * BCH + boff + j * 64) * 8];
        #pragma unroll
        for (int i2 = 0; i2 < 4; i2++)
            af[i2] = *(const bf16x8*)&lA[(slot * 1024 + aoff + (f0 + i2) * 64) * 8];
    };

#define MM(AF, BF, F0) do { \
    __builtin_amdgcn_s_setprio(1); \
    _Pragma("unroll") \
    for (int i2 = 0; i2 < 4; i2++) { \
        _Pragma("unroll") \
        for (int j = 0; j < MJ; j++) \
            acc[(F0) + i2][j] = __builtin_amdgcn_mfma_f32_16x16x32_bf16( \
                AF[i2], BF[j], acc[(F0) + i2][j], 0, 0, 0); \
    } \
    __builtin_amdgcn_s_setprio(0); } while (0)

#define BAR() __builtin_amdgcn_s_barrier()
    // counted wait: leave the 2 most recent half-slot stages (2+CB loads) in flight
#define VMWS() do { \
    if constexpr (CB == 2) asm volatile("s_waitcnt vmcnt(4)" ::: "memory"); \
    else                   asm volatile("s_waitcnt vmcnt(3)" ::: "memory"); } while (0)
#define VMW0() asm volatile("s_waitcnt vmcnt(0)" ::: "memory")

    const int T = K / 64;       // K-tiles (even)
    const int NIT = T / 2;

    // prologue: klo(0)->slot0, khi(0)->slot1, klo(1)->slot2
    STA(0); STB(0); STA(1); STB(1); STA(2); STB(2);
    VMWS();                     // slot0 + slot1 landed; slot2 in flight
    BAR();
    LD(af_a, bfr_a, 0, 0);      // fragments for ph1

    for (int it = 0; it < NIT; it++) {
        const bool nl = (it + 1 < NIT);
        // ph1: MM slot0 mg0 | LD-> ph2 (slot0 mg1) | stage A-khi(t+1)->slot3
        STA(3);
        BAR();
        MM(af_a, bfr_a, 0);
        LD(af_b, bfr_b, 0, 4);
        BAR();
        // ph2: MM slot0 mg1 | LD-> ph3 (slot1 mg0) | stage B-khi(t+1)->slot3
        STB(3);
        BAR();
        MM(af_b, bfr_b, 4);
        LD(af_a, bfr_a, 1, 0);
        BAR();
        // ph3: MM slot1 mg0 | LD-> ph4 (slot1 mg1) | stage A-klo(t+2)->slot0
        if (nl) STA(0);
        BAR();
        MM(af_a, bfr_a, 0);
        LD(af_b, bfr_b, 1, 4);
        BAR();
        // ph4: MM slot1 mg1 | LD-> ph5 (slot2 mg0) | stage B-klo(t+2)->slot0
        if (nl) STB(0);
        if (nl) { VMWS(); } else { VMW0(); }   // slot2 landed before its read
        BAR();
        MM(af_b, bfr_b, 4);
        LD(af_a, bfr_a, 2, 0);
        BAR();
        // ph5: MM slot2 mg0 | LD-> ph6 (slot2 mg1) | stage A-khi(t+2)->slot1
        if (nl) STA(1);
        BAR();
        MM(af_a, bfr_a, 0);
        LD(af_b, bfr_b, 2, 4);
        BAR();
        // ph6: MM slot2 mg1 | LD-> ph7 (slot3 mg0) | stage B-khi(t+2)->slot1
        if (nl) STB(1);
        BAR();
        MM(af_b, bfr_b, 4);
        LD(af_a, bfr_a, 3, 0);
        BAR();
        // ph7: MM slot3 mg0 | LD-> ph8 (slot3 mg1) | stage A-klo(t+3)->slot2
        if (nl) STA(2);
        BAR();
        MM(af_a, bfr_a, 0);
        LD(af_b, bfr_b, 3, 4);
        BAR();
        // ph8: MM slot3 mg1 | LD-> next ph1 (slot0 mg0) | stage B-klo(t+3)->slot2
        if (nl) STB(2);
        if (nl) VMWS();
        BAR();
        MM(af_b, bfr_b, 4);
        LD(af_a, bfr_a, 0, 0);   // tail: stale-but-valid read, feeds no MM
        BAR();
    }

#undef MM
#undef BAR
#undef VMWS
#undef VMW0

    // ---------------- epilogue ----------------
    float bv[MJ];
    if (HAS_BIAS) {
        #pragma unroll
        for (int j = 0; j < MJ; j++)
            bv[j] = args.bias[z][col0 + (wn * MJ + j) * 16 + r16];
    }

    void* C = args.C[z];
    const bool do_trans = ALLOW_TRANS && args.trans[z];

    #pragma unroll
    for (int i = 0; i < 8; i++) {
        const int m_base = row0 + (wm * 8 + i) * 16 + quad * 4;
        #pragma unroll
        for (int j = 0; j < MJ; j++) {
            const int n = col0 + (wn * MJ + j) * 16 + r16;
            if (ALLOW_TRANS && do_trans) {
                // C^T layout [N][M], bf16; 4 consecutive m -> one 8B store
                ushort4 o;
                float v0 = acc[i][j][0] * scale; if (HAS_BIAS) v0 += bv[j];
                float v1 = acc[i][j][1] * scale; if (HAS_BIAS) v1 += bv[j];
                float v2 = acc[i][j][2] * scale; if (HAS_BIAS) v2 += bv[j];
                float v3 = acc[i][j][3] * scale; if (HAS_BIAS) v3 += bv[j];
                o.x = f2bf(v0); o.y = f2bf(v1); o.z = f2bf(v2); o.w = f2bf(v3);
                *(ushort4*)((ushort_t*)C + (size_t)n * M + m_base) = o;
            } else {
                #pragma unroll
                for (int r = 0; r < 4; r++) {
                    float v = acc[i][j][r] * scale;
                    if (HAS_BIAS) v += bv[j];
                    size_t off = (size_t)(m_base + r) * N + n;
                    if (BF16_OUT) ((ushort_t*)C)[off] = f2bf(v);
                    else          ((float*)C)[off] = v;
                }
            }
        }
    }
}

// ---------- row softmax, in-place: S[row,0..4095] bf16, fp32 math ----------
struct SmArgs { ushort_t* S[2]; };

__global__ __launch_bounds__(256) void softmax_kernel(SmArgs a) {
    const int N = 4096;
    ushort_t* S = a.S[blockIdx.y];
    const int row = blockIdx.x;
    const int tid = threadIdx.x;
    const int lane = tid & 63;
    const int wave = tid >> 6;

    bf16x8* ptr = (bf16x8*)(S + (size_t)row * N);
    bf16x8 c0 = ptr[2 * tid];
    bf16x8 c1 = ptr[2 * tid + 1];

    float x[16];
    #pragma unroll
    for (int k = 0; k < 8; k++) {
        x[k]     = bf2f((ushort_t)c0[k]);
        x[8 + k] = bf2f((ushort_t)c1[k]);
    }

    float m = -3.4e38f;
    #pragma unroll
    for (int k = 0; k < 16; k++) m = fmaxf(m, x[k]);
    #pragma unroll
    for (int off = 32; off > 0; off >>= 1) m = fmaxf(m, __shfl_xor(m, off));

    __shared__ float redmax[4], redsum[4];
    if (lane == 0) redmax[wave] = m;
    __syncthreads();
    m = fmaxf(fmaxf(redmax[0], redmax[1]), fmaxf(redmax[2], redmax[3]));

    float s = 0.f;
    #pragma unroll
    for (int k = 0; k < 16; k++) { x[k] = __expf(x[k] - m); s += x[k]; }
    #pragma unroll
    for (int off = 32; off > 0; off >>= 1) s += __shfl_xor(s, off);
    if (lane == 0) redsum[wave] = s;
    __syncthreads();
    s = redsum[0] + redsum[1] + redsum[2] + redsum[3];
    const float inv = 1.0f / s;

    bf16x8 o0, o1;
    #pragma unroll
    for (int k = 0; k < 8; k++) {
        o0[k] = (short)f2bf(x[k] * inv);
        o1[k] = (short)f2bf(x[8 + k] * inv);
    }
    ptr[2 * tid]     = o0;
    ptr[2 * tid + 1] = o1;
}

// ---------- launch ----------
extern "C" void kernel_launch(void* const* d_in, const int* in_sizes, int n_in,
                              void* d_out, int out_size, void* d_ws, size_t ws_size,
                              hipStream_t stream) {
    (void)in_sizes; (void)n_in; (void)out_size;
    const int NC = 4096, NP = 4096, D = 1024;

    char* ws = (char*)d_ws;
    size_t off = 0;
    auto alloc = [&](size_t b) { size_t o = off; off += (b + 255) & ~(size_t)255; return o; };

    ushort_t* xb[6];
    for (int i = 0; i < 6; i++) xb[i] = (ushort_t*)(ws + alloc((size_t)NC * D * 2));
    ushort_t* wb[6];
    for (int i = 0; i < 6; i++) wb[i] = (ushort_t*)(ws + alloc((size_t)D * D * 2));
    ushort_t* qc  = (ushort_t*)(ws + alloc((size_t)NC * D * 2));
    ushort_t* kc  = (ushort_t*)(ws + alloc((size_t)NC * D * 2));
    ushort_t* qp  = (ushort_t*)(ws + alloc((size_t)NP * D * 2));
    ushort_t* kp  = (ushort_t*)(ws + alloc((size_t)NP * D * 2));
    ushort_t* vcT = (ushort_t*)(ws + alloc((size_t)NC * D * 2)); // [D][NC]
    ushort_t* vpT = (ushort_t*)(ws + alloc((size_t)NP * D * 2)); // [D][NP]
    ushort_t* Sb1 = (ushort_t*)(ws + alloc((size_t)4096 * 4096 * 2));
    ushort_t* Sb2 = (ushort_t*)(ws + alloc((size_t)4096 * 4096 * 2));

    if (ws_size < off) return;

    // convert inputs + weights to bf16 (one dispatch)
    CvtArgs ca;
    for (int i = 0; i < 6; i++) {
        ca.src[i] = (const float*)d_in[i];
        ca.dst[i] = xb[i];
        ca.n4[i] = NC * D / 4;
    }
    const int widx[6] = {6, 8, 10, 12, 14, 16};
    for (int i = 0; i < 6; i++) {
        ca.src[6 + i] = (const float*)d_in[widx[i]];
        ca.dst[6 + i] = wb[i];
        ca.n4[6 + i] = D * D / 4;
    }
    cvt_kernel<<<dim3(256, 12), 256, 0, stream>>>(ca);

    const dim3 blk(512);
    const float inv_scale = 1.0f / 32.0f; // 1/sqrt(D_OUT)

    float* out_c = (float*)d_out;                       // comp_fused [NC, D]
    float* out_p = (float*)d_out + (size_t)NC * D;      // prot_fused [NP, D]

    // --- 6 projections: 256x256 8-phase, K=1024; grid 384 blocks ---
    {
        GemmArgs<6> ga;
        ushort_t* outs[6] = {qc, kc, vcT, qp, kp, vpT};
        const int bidx[6] = {7, 9, 11, 13, 15, 17};
        for (int i = 0; i < 6; i++) {
            ga.A[i] = xb[i];
            ga.B[i] = wb[i];
            ga.bias[i] = (const float*)d_in[bidx[i]];
            ga.C[i] = outs[i];
            ga.trans[i] = (i == 2 || i == 5);   // v projections -> transposed
            ga.koff[i] = 0;
        }
        gemm256<6, 4, true, true, true>
            <<<dim3(NC / 256, D / 256, 6), blk, 0, stream>>>(ga, NC, D, D, D, 1.0f);
    }

    // --- 2 score GEMMs: 256x256 8-phase, K=1024; grid 512 = 2 rounds ---
    {
        GemmArgs<2> ga;
        ga.A[0] = qc; ga.B[0] = kp; ga.C[0] = Sb1;
        ga.A[1] = qp; ga.B[1] = kc; ga.C[1] = Sb2;
        ga.bias[0] = ga.bias[1] = nullptr;
        ga.trans[0] = ga.trans[1] = 0;
        ga.koff[0] = ga.koff[1] = 0;
        gemm256<2, 4, true, false, false>
            <<<dim3(4096 / 256, 4096 / 256, 2), blk, 0, stream>>>(
                ga, 4096, 4096, D, D, inv_scale);
    }

    // --- 2 softmaxes, one dispatch, in-place ---
    {
        SmArgs sa; sa.S[0] = Sb1; sa.S[1] = Sb2;
        softmax_kernel<<<dim3(4096, 2), dim3(256), 0, stream>>>(sa);
    }

    // --- PV: split-K=2, 256x256 tiles, fp32 out; grid (16,4,4) = 256 = 1/CU.
    //     sk=0 partials into the dead qc..kp region (32 MB contiguous);
    //     sk=1 straight to d_out; then d_out += part.
    {
        float* part = (float*)qc;                       // 2 x 4096 x 1024 fp32
        GemmArgs<4> ga;
        ga.A[0] = Sb1; ga.B[0] = vpT; ga.C[0] = part;                 ga.koff[0] = 0;
        ga.A[1] = Sb1; ga.B[1] = vpT; ga.C[1] = out_c;                ga.koff[1] = 2048;
        ga.A[2] = Sb2; ga.B[2] = vcT; ga.C[2] = part + (size_t)NP * D; ga.koff[2] = 0;
        ga.A[3] = Sb2; ga.B[3] = vcT; ga.C[3] = out_p;                ga.koff[3] = 2048;
        for (int i = 0; i < 4; i++) { ga.bias[i] = nullptr; ga.trans[i] = 0; }
        gemm256<4, 4, false, false, false>
            <<<dim3(4096 / 256, D / 256, 4), blk, 0, stream>>>(
                ga, 4096, D, 2048, 4096, 1.0f);

        add_kernel<<<dim3(2048), dim3(256), 0, stream>>>(
            (float*)d_out, part, 2 * NC * D / 4);
    }
}